// Round 1
// baseline (910.329 us; speedup 1.0000x reference)
//
#include <hip/hip_runtime.h>
#include <hip/hip_bf16.h>
#include <stdint.h>

// Problem constants
#define H_ 8
#define N_ 512
#define V_ 64
#define QL_ 64
#define VH_ 512
#define B_ 32
#define S_ 512

typedef __attribute__((ext_vector_type(8))) short short8;
typedef __attribute__((ext_vector_type(4))) float floatx4;
typedef __attribute__((ext_vector_type(4))) unsigned short ushortx4;

static __device__ __forceinline__ unsigned short f2bf(float x) {
    unsigned int u = __float_as_uint(x);
    unsigned int r = (u + 0x7fffu + ((u >> 16) & 1u)) >> 16;
    return (unsigned short)r;
}
static __device__ __forceinline__ float bf2f(unsigned short u) {
    return __uint_as_float(((unsigned int)u) << 16);
}

// ---------------- restage: f32 -> bf16 ----------------
__global__ __launch_bounds__(256) void k_cvt(const float4* __restrict__ src,
                                             ushortx4* __restrict__ dst, int n4) {
    int i = blockIdx.x * 256 + threadIdx.x;
    if (i < n4) {
        float4 v = src[i];
        ushortx4 o;
        o.x = f2bf(v.x); o.y = f2bf(v.y); o.z = f2bf(v.z); o.w = f2bf(v.w);
        dst[i] = o;
    }
}

// sigc = sigmoid(conn) (or 1.0 if !self_connection), bf16
__global__ __launch_bounds__(256) void k_sig(const float4* __restrict__ src,
                                             ushortx4* __restrict__ dst,
                                             const int* __restrict__ flag, int n4) {
    int i = blockIdx.x * 256 + threadIdx.x;
    int f = *flag;
    if (i < n4) {
        float4 v = src[i];
        ushortx4 o;
        o.x = f2bf(f ? 1.0f / (1.0f + __expf(-v.x)) : 1.0f);
        o.y = f2bf(f ? 1.0f / (1.0f + __expf(-v.y)) : 1.0f);
        o.z = f2bf(f ? 1.0f / (1.0f + __expf(-v.z)) : 1.0f);
        o.w = f2bf(f ? 1.0f / (1.0f + __expf(-v.w)) : 1.0f);
        dst[i] = o;
    }
}

// hidden_values [B][S][VH] f32 -> valst [B][H][V][S] bf16 (vals[b,h,s,v]=hv[b,s,v*8+h])
// block: (b, s-chunk of 64, vh-half of 256). LDS transpose.
__global__ __launch_bounds__(256) void k_vtrans(const float* __restrict__ hv,
                                                unsigned short* __restrict__ vt) {
    __shared__ __align__(16) unsigned short lds[256][72];
    int b = blockIdx.x, sc = blockIdx.y, half = blockIdx.z;
    int t = threadIdx.x;
    int s0 = sc * 64, vh0 = half * 256;
    // read 64 s x 256 vh f32, coalesced
    for (int rep = 0; rep < 16; ++rep) {
        int task = rep * 256 + t;          // 4096 float4
        int s = task >> 6, v4 = task & 63;
        float4 x = *(const float4*)&hv[((size_t)(b * 512 + s0 + s)) * 512 + vh0 + v4 * 4];
        lds[v4 * 4 + 0][s] = f2bf(x.x);
        lds[v4 * 4 + 1][s] = f2bf(x.y);
        lds[v4 * 4 + 2][s] = f2bf(x.z);
        lds[v4 * 4 + 3][s] = f2bf(x.w);
    }
    __syncthreads();
    // write 256 (h,v) rows x 64 s bf16, coalesced
    for (int rep = 0; rep < 8; ++rep) {
        int task = rep * 256 + t;          // 2048 uint4
        int rowi = task >> 3, seg = task & 7;
        int h = rowi >> 5, vl = rowi & 31;
        int v = half * 32 + vl;
        uint4 val = *(const uint4*)&lds[vl * 8 + h][seg * 8];
        *(uint4*)&vt[((size_t)(b * 512 + h * 64 + v)) * 512 + s0 + seg * 8] = val;
    }
}

// ---------------- attention ----------------
// grid (x=b 32, y=h*8+nt 64); block 256 = 4 waves; wave w owns n-rows [n0+16w, n0+16w+16)
__global__ __launch_bounds__(256) void k_attn(
    const unsigned short* __restrict__ qb,   // [H*N][64] bf16
    const unsigned short* __restrict__ kb,   // [B][S][64] bf16
    const unsigned short* __restrict__ vt,   // [B][H][V][S] bf16
    const unsigned short* __restrict__ sg,   // [H][N][S] bf16
    unsigned short* __restrict__ ao)         // [B][H][N][V] bf16
{
    __shared__ __align__(16) unsigned short Qs[64][72];
    __shared__ __align__(16) unsigned short Ks[128][72];
    __shared__ __align__(16) unsigned short Vs[64][136];
    __shared__ __align__(16) unsigned short Ps[64][136];

    int b = blockIdx.x;
    int h = blockIdx.y >> 3;
    int nt = blockIdx.y & 7;
    int n0 = nt * 64;
    int t = threadIdx.x;
    int w = t >> 6, l = t & 63;
    int c = l & 15, q = l >> 4;

    // stage Q tile: 64 rows x 128B = 512 uint4
    for (int rep = 0; rep < 2; ++rep) {
        int task = rep * 256 + t;
        int row = task >> 3, seg = task & 7;
        *(uint4*)&Qs[row][seg * 8] =
            *(const uint4*)&qb[((size_t)(h * 512 + n0 + row)) * 64 + seg * 8];
    }
    __syncthreads();

    // Q A-fragments (A[m=l&15][k=q*8+j]), k split in two 32-steps
    short8 qa0 = *(const short8*)&Qs[w * 16 + c][q * 8];
    short8 qa1 = *(const short8*)&Qs[w * 16 + c][32 + q * 8];

    floatx4 zero = {0.0f, 0.0f, 0.0f, 0.0f};
    floatx4 oacc[4];
    for (int i = 0; i < 4; ++i) oacc[i] = zero;
    float rsum[4] = {0.f, 0.f, 0.f, 0.f};

    for (int ch = 0; ch < 4; ++ch) {
        int s0 = ch * 128;
        // stage K chunk: 128 rows x 128 B = 1024 uint4
        for (int rep = 0; rep < 4; ++rep) {
            int task = rep * 256 + t;
            int row = task >> 3, seg = task & 7;
            *(uint4*)&Ks[row][seg * 8] =
                *(const uint4*)&kb[((size_t)(b * 512 + s0 + row)) * 64 + seg * 8];
        }
        // stage V chunk: 64 v-rows x 256 B = 1024 uint4
        for (int rep = 0; rep < 4; ++rep) {
            int task = rep * 256 + t;
            int row = task >> 4, seg = task & 15;
            *(uint4*)&Vs[row][seg * 8] =
                *(const uint4*)&vt[((size_t)((b * 8 + h) * 64 + row)) * 512 + s0 + seg * 8];
        }
        __syncthreads();

        // QK^T for this wave's 16 n-rows over 128 s
        floatx4 sacc[8];
        for (int st = 0; st < 8; ++st) {
            short8 kb0 = *(const short8*)&Ks[st * 16 + c][q * 8];
            short8 kb1 = *(const short8*)&Ks[st * 16 + c][32 + q * 8];
            floatx4 acc = zero;
            acc = __builtin_amdgcn_mfma_f32_16x16x32_bf16(qa0, kb0, acc, 0, 0, 0);
            acc = __builtin_amdgcn_mfma_f32_16x16x32_bf16(qa1, kb1, acc, 0, 0, 0);
            sacc[st] = acc;
        }
        // e = exp(score/8)*sig(c); accumulate row sums; write P chunk (bf16)
        float esum[4] = {0.f, 0.f, 0.f, 0.f};
        for (int st = 0; st < 8; ++st) {
            int s_g = s0 + st * 16 + c;
            for (int r = 0; r < 4; ++r) {
                int nl = w * 16 + q * 4 + r;           // C-layout: row=(l>>4)*4+r
                float scv = sacc[st][r] * 0.125f;
                float sgv = bf2f(sg[((size_t)(h * 512 + n0 + nl)) * 512 + s_g]);
                float e = __expf(scv) * sgv;
                esum[r] += e;
                Ps[nl][st * 16 + c] = f2bf(e);
            }
        }
        // butterfly over the 16 col-lanes (bits 0-3) -> full row sums of this chunk
        for (int m = 1; m <= 8; m <<= 1)
            for (int r = 0; r < 4; ++r) esum[r] += __shfl_xor(esum[r], m, 64);
        for (int r = 0; r < 4; ++r) rsum[r] += esum[r];
        __syncthreads();   // P visible

        // P @ V accumulate (A from own P rows, B from Vs)
        for (int k2 = 0; k2 < 4; ++k2) {
            short8 pa = *(const short8*)&Ps[w * 16 + c][k2 * 32 + q * 8];
            for (int vtile = 0; vtile < 4; ++vtile) {
                short8 vb = *(const short8*)&Vs[vtile * 16 + c][k2 * 32 + q * 8];
                oacc[vtile] = __builtin_amdgcn_mfma_f32_16x16x32_bf16(pa, vb, oacc[vtile], 0, 0, 0);
            }
        }
        __syncthreads();   // before restaging K/V/P next chunk
    }

    // divide by row sums (same lane holds matching rows) and store bf16
    for (int r = 0; r < 4; ++r) {
        float rcp = 1.0f / rsum[r];
        int n_g = n0 + w * 16 + q * 4 + r;
        for (int vtile = 0; vtile < 4; ++vtile) {
            float o = oacc[vtile][r] * rcp;
            ao[((size_t)((b * 8 + h) * 512 + n_g)) * 64 + vtile * 16 + c] = f2bf(o);
        }
    }
}

// ---------------- layernorm ----------------
// one wave per (b,n) row; read attn [B][H][N][V] bf16, write xln [N][B][VH] bf16
__global__ __launch_bounds__(256) void k_ln(
    const unsigned short* __restrict__ ao,
    const float* __restrict__ gamma, const float* __restrict__ beta,
    unsigned short* __restrict__ xln)
{
    __shared__ __align__(16) unsigned short xrow[4][512];
    __shared__ float gs[512], bs[512];
    int t = threadIdx.x;
    for (int i = t; i < 512; i += 256) { gs[i] = gamma[i]; bs[i] = beta[i]; }
    __syncthreads();
    int w = t >> 6, l = t & 63;
    int idx = blockIdx.x * 4 + w;
    int b = idx >> 9, n = idx & 511;
    int hh = l >> 3, vb = (l & 7) * 8;
    uint4 raw = *(const uint4*)&ao[((size_t)((b * 8 + hh) * 512 + n)) * 64 + vb];
    unsigned int u[4] = {raw.x, raw.y, raw.z, raw.w};
    float x[8];
    float sum = 0.f, ss = 0.f;
    for (int j = 0; j < 4; ++j) {
        x[2 * j]     = bf2f((unsigned short)(u[j] & 0xffffu));
        x[2 * j + 1] = bf2f((unsigned short)(u[j] >> 16));
    }
    for (int j = 0; j < 8; ++j) { sum += x[j]; ss += x[j] * x[j]; }
    for (int m = 1; m <= 32; m <<= 1) {
        sum += __shfl_xor(sum, m, 64);
        ss  += __shfl_xor(ss, m, 64);
    }
    float mu = sum * (1.0f / 512.0f);
    float var = ss * (1.0f / 512.0f) - mu * mu;
    float rstd = rsqrtf(var + 1e-12f);
    for (int j = 0; j < 8; ++j) {
        int vh = (vb + j) * 8 + hh;
        float y = (x[j] - mu) * rstd * gs[vh] + bs[vh];
        xrow[w][vh] = f2bf(y);
    }
    __syncthreads();
    uint4 outv = *(const uint4*)&xrow[w][l * 8];
    *(uint4*)&xln[((size_t)(n * 32 + b)) * 512 + l * 8] = outv;
}

// ---------------- per-neuron GEMM: out[b,n,:] = LN(x)[n,b,:] @ W[n] + bias[n] ----------------
// block per neuron n; W chunk (32 k x O) staged transposed to LDS as bf16; A read from global.
template<int O>
__global__ __launch_bounds__(256) void k_gemm(
    const unsigned short* __restrict__ xln,  // [N][B][VH] bf16
    const float* __restrict__ Wg,            // [N][512][O] f32
    const float* __restrict__ bias,          // [N][O] f32
    float* __restrict__ out)                 // [B][N][O] f32
{
    constexpr int OT = O / 64;               // o-tiles per wave
    __shared__ __align__(16) unsigned short Wc[O][40];
    int n = blockIdx.x;
    int t = threadIdx.x, w = t >> 6, l = t & 63;
    int c = l & 15, q = l >> 4;

    floatx4 zero = {0.0f, 0.0f, 0.0f, 0.0f};
    floatx4 acc[2][OT];
    for (int mt = 0; mt < 2; ++mt)
        for (int ot = 0; ot < OT; ++ot) acc[mt][ot] = zero;

    const unsigned short* a0p = &xln[((size_t)(n * 32 + c)) * 512];
    const unsigned short* a1p = &xln[((size_t)(n * 32 + 16 + c)) * 512];

    for (int kc = 0; kc < 16; ++kc) {
        for (int rep = 0; rep < O / 32; ++rep) {
            int task = rep * 256 + t;        // 8*O float4 tasks
            int k = task / (O / 4);
            int o4 = task % (O / 4);
            float4 v = *(const float4*)&Wg[(((size_t)n * 512) + kc * 32 + k) * O + o4 * 4];
            Wc[o4 * 4 + 0][k] = f2bf(v.x);
            Wc[o4 * 4 + 1][k] = f2bf(v.y);
            Wc[o4 * 4 + 2][k] = f2bf(v.z);
            Wc[o4 * 4 + 3][k] = f2bf(v.w);
        }
        __syncthreads();
        short8 a0 = *(const short8*)&a0p[kc * 32 + q * 8];
        short8 a1 = *(const short8*)&a1p[kc * 32 + q * 8];
        for (int ot = 0; ot < OT; ++ot) {
            short8 bw = *(const short8*)&Wc[(w * OT + ot) * 16 + c][q * 8];
            acc[0][ot] = __builtin_amdgcn_mfma_f32_16x16x32_bf16(a0, bw, acc[0][ot], 0, 0, 0);
            acc[1][ot] = __builtin_amdgcn_mfma_f32_16x16x32_bf16(a1, bw, acc[1][ot], 0, 0, 0);
        }
        __syncthreads();
    }
    for (int ot = 0; ot < OT; ++ot) {
        int o = (w * OT + ot) * 16 + c;
        float bv = bias[n * O + o];
        for (int mt = 0; mt < 2; ++mt) {
            for (int r = 0; r < 4; ++r) {
                int brow = mt * 16 + q * 4 + r;
                out[((size_t)(brow * 512 + n)) * O + o] = acc[mt][ot][r] + bv;
            }
        }
    }
}

extern "C" void kernel_launch(void* const* d_in, const int* in_sizes, int n_in,
                              void* d_out, int out_size, void* d_ws, size_t ws_size,
                              hipStream_t stream) {
    const float* hk    = (const float*)d_in[0];   // hidden_keys [32][512][64]
    const float* hv    = (const float*)d_in[1];   // hidden_values [32][512][512]
    const float* qb    = (const float*)d_in[2];   // query_bank [4096][64]
    const float* conn  = (const float*)d_in[3];   // connectivity [1][8][512][512]
    const float* gamma = (const float*)d_in[4];
    const float* beta  = (const float*)d_in[5];
    const float* kw    = (const float*)d_in[6];   // keys_w [512][512][64]
    const float* kbias = (const float*)d_in[7];   // keys_b [512][64]
    const float* vw    = (const float*)d_in[8];   // values_w [512][512][512]
    const float* vbias = (const float*)d_in[9];   // values_b [512][512]
    const int* flag    = (const int*)d_in[10];

    char* ws = (char*)d_ws;
    unsigned short* vts = (unsigned short*)ws;                      // 16 MB [B][H][V][S]
    unsigned short* sgc = (unsigned short*)(ws + (16u << 20));      // 4 MB  [H][N][S]
    unsigned short* kbf = (unsigned short*)(ws + (20u << 20));      // 2 MB  [B][S][64]
    unsigned short* qbf = (unsigned short*)(ws + (22u << 20));      // 0.5MB [H*N][64]
    unsigned short* aow = (unsigned short*)(ws + (23u << 20));      // 16 MB [B][H][N][V]
    unsigned short* xln = (unsigned short*)ws;                      // 16 MB [N][B][VH] (reuses vts)

    k_cvt<<<256, 256, 0, stream>>>((const float4*)qb, (ushortx4*)qbf, 65536);
    k_cvt<<<1024, 256, 0, stream>>>((const float4*)hk, (ushortx4*)kbf, 262144);
    k_sig<<<2048, 256, 0, stream>>>((const float4*)conn, (ushortx4*)sgc, flag, 524288);
    k_vtrans<<<dim3(32, 8, 2), 256, 0, stream>>>(hv, vts);
    k_attn<<<dim3(32, 64), 256, 0, stream>>>(qbf, kbf, vts, sgc, aow);
    k_ln<<<4096, 256, 0, stream>>>(aow, gamma, beta, xln);
    k_gemm<64><<<512, 256, 0, stream>>>(xln, kw, kbias, (float*)d_out);
    k_gemm<512><<<512, 256, 0, stream>>>(xln, vw, vbias, (float*)d_out + 1048576);
}

// Round 2
// 883.470 us; speedup vs baseline: 1.0304x; 1.0304x over previous
//
#include <hip/hip_runtime.h>
#include <hip/hip_bf16.h>
#include <stdint.h>

// Problem constants
#define H_ 8
#define N_ 512
#define V_ 64
#define QL_ 64
#define VH_ 512
#define B_ 32
#define S_ 512

typedef __attribute__((ext_vector_type(8))) short short8;
typedef __attribute__((ext_vector_type(4))) float floatx4;
typedef __attribute__((ext_vector_type(4))) unsigned short ushortx4;

static __device__ __forceinline__ unsigned short f2bf(float x) {
    unsigned int u = __float_as_uint(x);
    unsigned int r = (u + 0x7fffu + ((u >> 16) & 1u)) >> 16;
    return (unsigned short)r;
}
static __device__ __forceinline__ float bf2f(unsigned short u) {
    return __uint_as_float(((unsigned int)u) << 16);
}
static __device__ __forceinline__ unsigned int pack2(float lo, float hi) {
    return (unsigned int)f2bf(lo) | ((unsigned int)f2bf(hi) << 16);
}

// ---------------- restage: f32 -> bf16 ----------------
__global__ __launch_bounds__(256) void k_cvt(const float4* __restrict__ src,
                                             ushortx4* __restrict__ dst, int n4) {
    int i = blockIdx.x * 256 + threadIdx.x;
    if (i < n4) {
        float4 v = src[i];
        ushortx4 o;
        o.x = f2bf(v.x); o.y = f2bf(v.y); o.z = f2bf(v.z); o.w = f2bf(v.w);
        dst[i] = o;
    }
}

// sigc = sigmoid(conn) (or 1.0 if !self_connection), bf16
__global__ __launch_bounds__(256) void k_sig(const float4* __restrict__ src,
                                             ushortx4* __restrict__ dst,
                                             const int* __restrict__ flag, int n4) {
    int i = blockIdx.x * 256 + threadIdx.x;
    int f = *flag;
    if (i < n4) {
        float4 v = src[i];
        ushortx4 o;
        o.x = f2bf(f ? 1.0f / (1.0f + __expf(-v.x)) : 1.0f);
        o.y = f2bf(f ? 1.0f / (1.0f + __expf(-v.y)) : 1.0f);
        o.z = f2bf(f ? 1.0f / (1.0f + __expf(-v.z)) : 1.0f);
        o.w = f2bf(f ? 1.0f / (1.0f + __expf(-v.w)) : 1.0f);
        dst[i] = o;
    }
}

// hidden_values [B][S][VH] f32 -> valst [B][H][V][S] bf16 (vals[b,h,s,v]=hv[b,s,v*8+h])
// Pair-packed LDS transpose: T[vh_local][s2] dwords, dword = (bf16(s even), bf16(s odd)).
// Write banks = 16*vh4 + 4j + s2 with s2 across lanes -> 2-way (free). Reads/stores coalesced.
__global__ __launch_bounds__(256) void k_vtrans(const float* __restrict__ hv,
                                                unsigned short* __restrict__ vt) {
    __shared__ __align__(16) unsigned int T[256][36];
    int b = blockIdx.x, sc = blockIdx.y, half = blockIdx.z;
    int t = threadIdx.x;
    int s0 = sc * 64, vh0 = half * 256;
    int s2 = t & 31;
    for (int rep = 0; rep < 8; ++rep) {
        int vh4 = rep * 8 + (t >> 5);
        const float* g = &hv[((size_t)(b * 512 + s0 + 2 * s2)) * 512 + vh0 + vh4 * 4];
        float4 lo = *(const float4*)g;
        float4 hi = *(const float4*)(g + 512);
        T[vh4 * 4 + 0][s2] = pack2(lo.x, hi.x);
        T[vh4 * 4 + 1][s2] = pack2(lo.y, hi.y);
        T[vh4 * 4 + 2][s2] = pack2(lo.z, hi.z);
        T[vh4 * 4 + 3][s2] = pack2(lo.w, hi.w);
    }
    __syncthreads();
    for (int rep = 0; rep < 8; ++rep) {
        int row = rep * 32 + (t >> 3);
        int m = t & 7;
        uint4 d = *(const uint4*)&T[row][m * 4];
        int h = row & 7, v = half * 32 + (row >> 3);
        *(uint4*)&vt[((size_t)((b * 8 + h) * 64 + v)) * 512 + s0 + m * 8] = d;
    }
}

// ---------------- attention ----------------
// grid (x=b 32, y=h*8+nt 64); block 256 = 4 waves; wave w owns n-rows [n0+16w, n0+16w+16)
__global__ __launch_bounds__(256) void k_attn(
    const unsigned short* __restrict__ qb,   // [H*N][64] bf16
    const unsigned short* __restrict__ kb,   // [B][S][64] bf16
    const unsigned short* __restrict__ vt,   // [B][H][V][S] bf16
    const unsigned short* __restrict__ sg,   // [H][N][S] bf16
    unsigned short* __restrict__ ao)         // [B][H][N][V] bf16
{
    __shared__ __align__(16) unsigned short Qs[64][72];
    __shared__ __align__(16) unsigned short Ks[128][72];
    __shared__ __align__(16) unsigned short Vs[64][136];
    __shared__ __align__(16) unsigned short Ps[64][136];

    int b = blockIdx.x;
    int h = blockIdx.y >> 3;
    int nt = blockIdx.y & 7;
    int n0 = nt * 64;
    int t = threadIdx.x;
    int w = t >> 6, l = t & 63;
    int c = l & 15, q = l >> 4;

    // stage Q tile: 64 rows x 128B = 512 uint4
    for (int rep = 0; rep < 2; ++rep) {
        int task = rep * 256 + t;
        int row = task >> 3, seg = task & 7;
        *(uint4*)&Qs[row][seg * 8] =
            *(const uint4*)&qb[((size_t)(h * 512 + n0 + row)) * 64 + seg * 8];
    }
    __syncthreads();

    // Q A-fragments (A[m=l&15][k=q*8+j]), k split in two 32-steps
    short8 qa0 = *(const short8*)&Qs[w * 16 + c][q * 8];
    short8 qa1 = *(const short8*)&Qs[w * 16 + c][32 + q * 8];

    floatx4 zero = {0.0f, 0.0f, 0.0f, 0.0f};
    floatx4 oacc[4];
    for (int i = 0; i < 4; ++i) oacc[i] = zero;
    float rsum[4] = {0.f, 0.f, 0.f, 0.f};

    for (int ch = 0; ch < 4; ++ch) {
        int s0 = ch * 128;
        // stage K chunk: 128 rows x 128 B = 1024 uint4
        for (int rep = 0; rep < 4; ++rep) {
            int task = rep * 256 + t;
            int row = task >> 3, seg = task & 7;
            *(uint4*)&Ks[row][seg * 8] =
                *(const uint4*)&kb[((size_t)(b * 512 + s0 + row)) * 64 + seg * 8];
        }
        // stage V chunk: 64 v-rows x 256 B = 1024 uint4
        for (int rep = 0; rep < 4; ++rep) {
            int task = rep * 256 + t;
            int row = task >> 4, seg = task & 15;
            *(uint4*)&Vs[row][seg * 8] =
                *(const uint4*)&vt[((size_t)((b * 8 + h) * 64 + row)) * 512 + s0 + seg * 8];
        }
        __syncthreads();

        // QK^T for this wave's 16 n-rows over 128 s
        floatx4 sacc[8];
        for (int st = 0; st < 8; ++st) {
            short8 kb0 = *(const short8*)&Ks[st * 16 + c][q * 8];
            short8 kb1 = *(const short8*)&Ks[st * 16 + c][32 + q * 8];
            floatx4 acc = zero;
            acc = __builtin_amdgcn_mfma_f32_16x16x32_bf16(qa0, kb0, acc, 0, 0, 0);
            acc = __builtin_amdgcn_mfma_f32_16x16x32_bf16(qa1, kb1, acc, 0, 0, 0);
            sacc[st] = acc;
        }
        // e = exp(score/8)*sig(c); accumulate row sums; write P chunk (bf16)
        float esum[4] = {0.f, 0.f, 0.f, 0.f};
        for (int st = 0; st < 8; ++st) {
            int s_g = s0 + st * 16 + c;
            for (int r = 0; r < 4; ++r) {
                int nl = w * 16 + q * 4 + r;           // C-layout: row=(l>>4)*4+r
                float scv = sacc[st][r] * 0.125f;
                float sgv = bf2f(sg[((size_t)(h * 512 + n0 + nl)) * 512 + s_g]);
                float e = __expf(scv) * sgv;
                esum[r] += e;
                Ps[nl][st * 16 + c] = f2bf(e);
            }
        }
        // butterfly over the 16 col-lanes (bits 0-3) -> full row sums of this chunk
        for (int m = 1; m <= 8; m <<= 1)
            for (int r = 0; r < 4; ++r) esum[r] += __shfl_xor(esum[r], m, 64);
        for (int r = 0; r < 4; ++r) rsum[r] += esum[r];
        __syncthreads();   // P visible

        // P @ V accumulate (A from own P rows, B from Vs)
        for (int k2 = 0; k2 < 4; ++k2) {
            short8 pa = *(const short8*)&Ps[w * 16 + c][k2 * 32 + q * 8];
            for (int vtile = 0; vtile < 4; ++vtile) {
                short8 vb = *(const short8*)&Vs[vtile * 16 + c][k2 * 32 + q * 8];
                oacc[vtile] = __builtin_amdgcn_mfma_f32_16x16x32_bf16(pa, vb, oacc[vtile], 0, 0, 0);
            }
        }
        __syncthreads();   // before restaging K/V/P next chunk
    }

    // divide by row sums (same lane holds matching rows) and store bf16
    for (int r = 0; r < 4; ++r) {
        float rcp = 1.0f / rsum[r];
        int n_g = n0 + w * 16 + q * 4 + r;
        for (int vtile = 0; vtile < 4; ++vtile) {
            float o = oacc[vtile][r] * rcp;
            ao[((size_t)((b * 8 + h) * 512 + n_g)) * 64 + vtile * 16 + c] = f2bf(o);
        }
    }
}

// ---------------- layernorm ----------------
// one wave per (b,n) row; read attn [B][H][N][V] bf16, write xln [N][B][VH] bf16
__global__ __launch_bounds__(256) void k_ln(
    const unsigned short* __restrict__ ao,
    const float* __restrict__ gamma, const float* __restrict__ beta,
    unsigned short* __restrict__ xln)
{
    __shared__ __align__(16) unsigned short xrow[4][512];
    __shared__ float gs[512], bs[512];
    int t = threadIdx.x;
    for (int i = t; i < 512; i += 256) { gs[i] = gamma[i]; bs[i] = beta[i]; }
    __syncthreads();
    int w = t >> 6, l = t & 63;
    int idx = blockIdx.x * 4 + w;
    int b = idx >> 9, n = idx & 511;
    int hh = l >> 3, vb = (l & 7) * 8;
    uint4 raw = *(const uint4*)&ao[((size_t)((b * 8 + hh) * 512 + n)) * 64 + vb];
    unsigned int u[4] = {raw.x, raw.y, raw.z, raw.w};
    float x[8];
    float sum = 0.f, ss = 0.f;
    for (int j = 0; j < 4; ++j) {
        x[2 * j]     = bf2f((unsigned short)(u[j] & 0xffffu));
        x[2 * j + 1] = bf2f((unsigned short)(u[j] >> 16));
    }
    for (int j = 0; j < 8; ++j) { sum += x[j]; ss += x[j] * x[j]; }
    for (int m = 1; m <= 32; m <<= 1) {
        sum += __shfl_xor(sum, m, 64);
        ss  += __shfl_xor(ss, m, 64);
    }
    float mu = sum * (1.0f / 512.0f);
    float var = ss * (1.0f / 512.0f) - mu * mu;
    float rstd = rsqrtf(var + 1e-12f);
    for (int j = 0; j < 8; ++j) {
        int vh = (vb + j) * 8 + hh;
        float y = (x[j] - mu) * rstd * gs[vh] + bs[vh];
        xrow[w][vh] = f2bf(y);
    }
    __syncthreads();
    uint4 outv = *(const uint4*)&xrow[w][l * 8];
    *(uint4*)&xln[((size_t)(n * 32 + b)) * 512 + l * 8] = outv;
}

// ---------------- per-neuron GEMM: out[b,n,:] = LN(x)[n,b,:] @ W[n] + bias[n] ----------------
// Block per neuron n. W staged to LDS as PAIR-PACKED dwords T[o][k2] (dword = bf16 pair of
// consecutive k): write banks = 16*(j&1)+k2 with k2 across lanes + j rotation -> 2-way (free);
// B-fragment = one aligned ds_read_b128 of 4 consecutive k2 dwords = exact short8 k-order.
template<int O>
__global__ __launch_bounds__(256) void k_gemm(
    const unsigned short* __restrict__ xln,  // [N][B][VH] bf16
    const float* __restrict__ Wg,            // [N][512][O] f32
    const float* __restrict__ bias,          // [N][O] f32
    float* __restrict__ out)                 // [B][N][O] f32
{
    constexpr int OT = O / 64;               // o-tiles per wave
    constexpr int REPS = O / 64;             // pair-tasks per thread per kc-chunk
    __shared__ __align__(16) unsigned int T[O][16];   // [o][k2] dwords, row 64 B
    int n = blockIdx.x;
    int t = threadIdx.x, w = t >> 6, l = t & 63;
    int c = l & 15, q = l >> 4;
    int k2l = t & 15;
    int rot = t >> 4;

    floatx4 zero = {0.0f, 0.0f, 0.0f, 0.0f};
    floatx4 acc[2][OT];
    for (int mt = 0; mt < 2; ++mt)
        for (int ot = 0; ot < OT; ++ot) acc[mt][ot] = zero;

    const unsigned short* a0p = &xln[((size_t)(n * 32 + c)) * 512];
    const unsigned short* a1p = &xln[((size_t)(n * 32 + 16 + c)) * 512];

    for (int kc = 0; kc < 16; ++kc) {
        #pragma unroll
        for (int rep = 0; rep < REPS; ++rep) {
            int o4 = rep * 16 + (t >> 4);
            const float* g0 = &Wg[(((size_t)n * 512) + kc * 32 + 2 * k2l) * O + o4 * 4];
            float4 lo = *(const float4*)g0;
            float4 hi = *(const float4*)(g0 + O);
            unsigned int d[4];
            d[0] = pack2(lo.x, hi.x);
            d[1] = pack2(lo.y, hi.y);
            d[2] = pack2(lo.z, hi.z);
            d[3] = pack2(lo.w, hi.w);
            #pragma unroll
            for (int i = 0; i < 4; ++i) {
                int j = (rot + i) & 3;
                T[o4 * 4 + j][k2l] = d[j];
            }
        }
        __syncthreads();
        short8 a0 = *(const short8*)&a0p[kc * 32 + q * 8];
        short8 a1 = *(const short8*)&a1p[kc * 32 + q * 8];
        #pragma unroll
        for (int ot = 0; ot < OT; ++ot) {
            short8 bw = *(const short8*)&T[(w * OT + ot) * 16 + c][q * 4];
            acc[0][ot] = __builtin_amdgcn_mfma_f32_16x16x32_bf16(a0, bw, acc[0][ot], 0, 0, 0);
            acc[1][ot] = __builtin_amdgcn_mfma_f32_16x16x32_bf16(a1, bw, acc[1][ot], 0, 0, 0);
        }
        __syncthreads();
    }
    for (int ot = 0; ot < OT; ++ot) {
        int o = (w * OT + ot) * 16 + c;
        float bv = bias[n * O + o];
        for (int mt = 0; mt < 2; ++mt) {
            for (int r = 0; r < 4; ++r) {
                int brow = mt * 16 + q * 4 + r;
                out[((size_t)(brow * 512 + n)) * O + o] = acc[mt][ot][r] + bv;
            }
        }
    }
}

extern "C" void kernel_launch(void* const* d_in, const int* in_sizes, int n_in,
                              void* d_out, int out_size, void* d_ws, size_t ws_size,
                              hipStream_t stream) {
    const float* hk    = (const float*)d_in[0];   // hidden_keys [32][512][64]
    const float* hv    = (const float*)d_in[1];   // hidden_values [32][512][512]
    const float* qb    = (const float*)d_in[2];   // query_bank [4096][64]
    const float* conn  = (const float*)d_in[3];   // connectivity [1][8][512][512]
    const float* gamma = (const float*)d_in[4];
    const float* beta  = (const float*)d_in[5];
    const float* kw    = (const float*)d_in[6];   // keys_w [512][512][64]
    const float* kbias = (const float*)d_in[7];   // keys_b [512][64]
    const float* vw    = (const float*)d_in[8];   // values_w [512][512][512]
    const float* vbias = (const float*)d_in[9];   // values_b [512][512]
    const int* flag    = (const int*)d_in[10];

    char* ws = (char*)d_ws;
    unsigned short* vts = (unsigned short*)ws;                      // 16 MB [B][H][V][S]
    unsigned short* sgc = (unsigned short*)(ws + (16u << 20));      // 4 MB  [H][N][S]
    unsigned short* kbf = (unsigned short*)(ws + (20u << 20));      // 2 MB  [B][S][64]
    unsigned short* qbf = (unsigned short*)(ws + (22u << 20));      // 0.5MB [H*N][64]
    unsigned short* aow = (unsigned short*)(ws + (23u << 20));      // 16 MB [B][H][N][V]
    unsigned short* xln = (unsigned short*)ws;                      // 16 MB [N][B][VH] (reuses vts)

    k_cvt<<<256, 256, 0, stream>>>((const float4*)qb, (ushortx4*)qbf, 65536);
    k_cvt<<<1024, 256, 0, stream>>>((const float4*)hk, (ushortx4*)kbf, 262144);
    k_sig<<<2048, 256, 0, stream>>>((const float4*)conn, (ushortx4*)sgc, flag, 524288);
    k_vtrans<<<dim3(32, 8, 2), 256, 0, stream>>>(hv, vts);
    k_attn<<<dim3(32, 64), 256, 0, stream>>>(qbf, kbf, vts, sgc, aow);
    k_ln<<<4096, 256, 0, stream>>>(aow, gamma, beta, xln);
    k_gemm<64><<<512, 256, 0, stream>>>(xln, kw, kbias, (float*)d_out);
    k_gemm<512><<<512, 256, 0, stream>>>(xln, vw, vbias, (float*)d_out + 1048576);
}